// Round 2
// baseline (8590.826 us; speedup 1.0000x reference)
//
#include <hip/hip_runtime.h>
#include <cstdint>

typedef short bf16x8 __attribute__((ext_vector_type(8)));
typedef float f32x4  __attribute__((ext_vector_type(4)));

constexpr int Bn = 16, Tn = 2048, Dn = 512, Hn = 512;
constexpr int NWG = 32;        // j-slice workgroups (16 h-columns each)
constexpr int JT  = Hn / NWG;  // 16
constexpr int NTHREADS = 256;  // 4 waves
constexpr int KW = 128;        // K-range per wave (4 MFMA k-steps of 32)

#define ALD(p)    __hip_atomic_load((p),      __ATOMIC_RELAXED, __HIP_MEMORY_SCOPE_AGENT)
#define AST(p, v) __hip_atomic_store((p), (v), __ATOMIC_RELAXED, __HIP_MEMORY_SCOPE_AGENT)

__device__ __forceinline__ unsigned short f2bf(float f) {
  union { float f; unsigned u; } v; v.f = f;
  unsigned r = v.u + 0x7FFFu + ((v.u >> 16) & 1u);   // RNE
  return (unsigned short)(r >> 16);
}

__global__ __launch_bounds__(NTHREADS, 1) void gru_scan(
    const float* __restrict__ x, const int* __restrict__ start,
    const float* __restrict__ w_ih, const float* __restrict__ w_hh,
    const float* __restrict__ b_ih, const float* __restrict__ b_hh,
    float* __restrict__ out, unsigned* __restrict__ h_u32,
    unsigned* __restrict__ flags)
{
  const int tid  = threadIdx.x;
  const int lane = tid & 63;
  const int wv   = tid >> 6;
  const int j0   = blockIdx.x * JT;
  const int kb   = wv * KW;
  const int arow = lane & 15;        // A row (batch) / B col (gate-within-tile)
  const int koff = (lane >> 4) * 8;  // k offset within 32-wide k-step
  const int g64  = lane >> 4;        // for LDS swizzle

  // ---- persistent weight B-fragments in registers (bf16) ----
  bf16x8 whf[3][4], wif[3][4];
  #pragma unroll
  for (int g = 0; g < 3; ++g) {
    const int grow = g * Hn + j0 + arow;
    #pragma unroll
    for (int s = 0; s < 4; ++s) {
      const int kk = kb + s * 32 + koff;
      const float* ph = w_hh + (size_t)grow * Dn + kk;
      const float* pi = w_ih + (size_t)grow * Dn + kk;
      bf16x8 a, b;
      #pragma unroll
      for (int i = 0; i < 8; ++i) { a[i] = (short)f2bf(ph[i]); b[i] = (short)f2bf(pi[i]); }
      whf[g][s] = a; wif[g][s] = b;
    }
  }

  // ---- per-thread epilogue constants: thread tid -> (batch bq, col jg) ----
  const int bq = tid >> 4;
  const int jj = tid & 15;
  const int jg = j0 + jj;
  const float bias_r  = b_ih[jg]          + b_hh[jg];
  const float bias_z  = b_ih[Hn + jg]     + b_hh[Hn + jg];
  const float bias_nx = b_ih[2 * Hn + jg];
  const float bias_nh = b_hh[2 * Hn + jg];
  const int   start_g = start[bq];
  const int   start_a = start[arow];
  // reader-side swizzled LDS slot (matches writer swizzle below)
  const int   slot_r  = (bq >> 2) * 64 + (((bq & 3) ^ (bq >> 2)) << 4) + jj;

  float h_own = 0.f;                      // this thread's h[bq][jg], kept in f32
  __shared__ float red[4][4][NTHREADS];   // [r/z/nx/nh][wave][swizzled pos]

  const float* xrow   = x + (size_t)arow * Tn * Dn + kb + koff;
  const float* xres_p = x + (size_t)bq   * Tn * Dn + jg;
  const int    fidx   = 32 * wv + (lane & 31);     // flags this wave polls
  const int    fown   = (blockIdx.x << 2) + wv;    // flag this wave posts

  #pragma unroll 1
  for (int t = 0; t < Tn; ++t) {
    // -------- phase A: input projection (overlaps other WGs' tail) --------
    const float* xt = xrow + (size_t)t * Dn;
    f32x4 xa[4][2];
    #pragma unroll
    for (int s = 0; s < 4; ++s) {
      xa[s][0] = *(const f32x4*)(xt + s * 32);
      xa[s][1] = *(const f32x4*)(xt + s * 32 + 4);
    }
    const float xres = xres_p[(size_t)t * Dn];
    bf16x8 xf[4];
    #pragma unroll
    for (int s = 0; s < 4; ++s) {
      bf16x8 v;
      #pragma unroll
      for (int i = 0; i < 4; ++i) {
        v[i]     = (short)f2bf(xa[s][0][i]);
        v[4 + i] = (short)f2bf(xa[s][1][i]);
      }
      xf[s] = v;
    }
    f32x4 ar = {0,0,0,0}, az = {0,0,0,0}, anx = {0,0,0,0}, anh = {0,0,0,0};
    #pragma unroll
    for (int s = 0; s < 4; ++s) {
      ar  = __builtin_amdgcn_mfma_f32_16x16x32_bf16(xf[s], wif[0][s], ar,  0, 0, 0);
      az  = __builtin_amdgcn_mfma_f32_16x16x32_bf16(xf[s], wif[1][s], az,  0, 0, 0);
      anx = __builtin_amdgcn_mfma_f32_16x16x32_bf16(xf[s], wif[2][s], anx, 0, 0, 0);
    }

    // -------- phase B: per-wave poll of this K-slice's 32 producer flags --------
    if (t > 0) {
      for (;;) {
        const unsigned f = ALD(&flags[fidx]);
        if (__all(f >= (unsigned)t)) break;
      }
      asm volatile("" ::: "memory");   // no hoisting h loads above the poll
    }

    // -------- phase C: hidden projection (cache-bypassing h loads) --------
    const bool am = (start_a < t);
    const unsigned* hb =
        h_u32 + (size_t)(t & 1) * (Bn * Hn / 2) + ((arow * Hn + kb + koff) >> 1);
    unsigned hu[4][4];
    #pragma unroll
    for (int s = 0; s < 4; ++s)
      #pragma unroll
      for (int i = 0; i < 4; ++i)
        hu[s][i] = ALD(hb + s * 16 + i);
    #pragma unroll
    for (int s = 0; s < 4; ++s) {
      union { unsigned u[4]; bf16x8 v; } hw;
      #pragma unroll
      for (int i = 0; i < 4; ++i) hw.u[i] = am ? hu[s][i] : 0u;
      ar  = __builtin_amdgcn_mfma_f32_16x16x32_bf16(hw.v, whf[0][s], ar,  0, 0, 0);
      az  = __builtin_amdgcn_mfma_f32_16x16x32_bf16(hw.v, whf[1][s], az,  0, 0, 0);
      anh = __builtin_amdgcn_mfma_f32_16x16x32_bf16(hw.v, whf[2][s], anh, 0, 0, 0);
    }

    // -------- phase D: cross-wave reduce (swizzled slots) + gates --------
    #pragma unroll
    for (int i = 0; i < 4; ++i) {
      const int pos = g64 * 64 + ((i ^ g64) << 4) + arow;  // 2-way max on 32 banks
      red[0][wv][pos] = ar[i];
      red[1][wv][pos] = az[i];
      red[2][wv][pos] = anx[i];
      red[3][wv][pos] = anh[i];
    }
    __syncthreads();
    float sr = bias_r, sz = bias_z, snx = bias_nx, snh = bias_nh;
    #pragma unroll
    for (int w2 = 0; w2 < 4; ++w2) {
      sr  += red[0][w2][slot_r];
      sz  += red[1][w2][slot_r];
      snx += red[2][w2][slot_r];
      snh += red[3][w2][slot_r];
    }
    const float r  = 1.f / (1.f + __expf(-sr));
    const float z  = 1.f / (1.f + __expf(-sz));
    const float ea = __expf(2.f * (snx + r * snh));
    const float n  = 1.f - 2.f / (ea + 1.f);             // NaN-safe tanh
    const float hm = (start_g < t) ? h_own : 0.f;
    const float hn = (1.f - z) * n + z * hm;
    h_own = hn;

    // -------- phase E: publish h(t+1) (paired bf16, cache-bypassing) --------
    const unsigned short hb16 = f2bf(hn);
    const unsigned partner = (unsigned)__shfl_xor((int)hb16, 1, 64) & 0xFFFFu;
    if (!(tid & 1)) {
      const unsigned packed = ((unsigned)hb16 & 0xFFFFu) | (partner << 16);
      AST(h_u32 + (size_t)((t + 1) & 1) * (Bn * Hn / 2) + ((bq * Hn + jg) >> 1), packed);
    }
    asm volatile("s_waitcnt vmcnt(0)" ::: "memory");     // h stores acked at LLC
    if (lane == 0) AST(&flags[fown], (unsigned)(t + 1));

    // -------- off-critical-path outputs (non-temporal, don't dirty L2) --------
    const size_t oo = ((size_t)bq * Tn + t) * Hn + jg;
    __builtin_nontemporal_store(xres + hn, &out[oo]);
    __builtin_nontemporal_store(hn, &out[(size_t)Bn * Tn * Hn + oo]);
  }
}

extern "C" void kernel_launch(void* const* d_in, const int* in_sizes, int n_in,
                              void* d_out, int out_size, void* d_ws, size_t ws_size,
                              hipStream_t stream) {
  const float* x     = (const float*)d_in[0];
  const int*   start = (const int*)d_in[1];
  const float* w_ih  = (const float*)d_in[2];
  const float* w_hh  = (const float*)d_in[3];
  const float* b_ih  = (const float*)d_in[4];
  const float* b_hh  = (const float*)d_in[5];
  float* out = (float*)d_out;

  // ws layout: [0,1KB) per-wave flags (128 used), [1KB, 1KB+32KB) ping-pong h (2xbf16 dwords)
  unsigned* flags = (unsigned*)d_ws;
  unsigned* h_u32 = (unsigned*)((char*)d_ws + 1024);

  hipMemsetAsync(d_ws, 0, 1024, stream);  // reset flags each launch (graph-safe)
  hipLaunchKernelGGL(gru_scan, dim3(NWG), dim3(NTHREADS), 0, stream,
                     x, start, w_ih, w_hh, b_ih, b_hh, out, h_u32, flags);
}

// Round 3
// 6487.696 us; speedup vs baseline: 1.3242x; 1.3242x over previous
//
#include <hip/hip_runtime.h>
#include <cstdint>

typedef short bf16x8 __attribute__((ext_vector_type(8)));
typedef float f32x4  __attribute__((ext_vector_type(4)));
typedef unsigned u32x4 __attribute__((ext_vector_type(4)));

constexpr int Bn = 16, Tn = 2048, Dn = 512, Hn = 512;
constexpr int NWG = 16;        // j-slice workgroups (32 h-columns each)
constexpr int JWG = 32;
constexpr int NTH = 512;       // 8 waves: (kw = wv&3) x (jw = wv>>2)

__device__ __forceinline__ unsigned short f2bf(float f) {
  union { float f; unsigned u; } v; v.f = f;
  unsigned r = v.u + 0x7FFFu + ((v.u >> 16) & 1u);   // RNE
  return (unsigned short)(r >> 16);
}

__global__ __launch_bounds__(NTH, 2) void gru_scan(
    const float* __restrict__ x, const int* __restrict__ start,
    const float* __restrict__ w_ih, const float* __restrict__ w_hh,
    const float* __restrict__ b_ih, const float* __restrict__ b_hh,
    float* __restrict__ out, unsigned short* __restrict__ ring)
{
  const int tid  = threadIdx.x;
  const int lane = tid & 63;
  const int wv   = tid >> 6;
  const int kw   = wv & 3;           // K-slice 128*kw
  const int jw   = wv >> 2;          // 16-col half within WG
  const int arow = lane & 15;        // A row (batch) / B col index
  const int koff = (lane >> 4) * 8;
  const int j0w  = blockIdx.x * JWG + jw * 16;
  const int kb   = kw * 128;

  // ---- persistent weight B-fragments in registers (bf16, loaded once) ----
  bf16x8 whf[3][4], wif[3][4];
  #pragma unroll
  for (int g = 0; g < 3; ++g) {
    const int grow = g * Hn + j0w + arow;
    #pragma unroll
    for (int s = 0; s < 4; ++s) {
      const int kk = kb + s * 32 + koff;
      const float* ph = w_hh + (size_t)grow * Dn + kk;
      const float* pi = w_ih + (size_t)grow * Dn + kk;
      bf16x8 a, b;
      #pragma unroll
      for (int i = 0; i < 8; ++i) { a[i] = (short)f2bf(ph[i]); b[i] = (short)f2bf(pi[i]); }
      whf[g][s] = a; wif[g][s] = b;
    }
  }

  // ---- per-thread epilogue mapping: tid -> (batch bq, col jj) ----
  const int bq = tid >> 5;
  const int jj = tid & 31;
  const int jg = blockIdx.x * JWG + jj;
  const float bias_r  = b_ih[jg]          + b_hh[jg];
  const float bias_z  = b_ih[Hn + jg]     + b_hh[Hn + jg];
  const float bias_nx = b_ih[2 * Hn + jg];
  const float bias_nh = b_hh[2 * Hn + jg];
  const int   start_g = start[bq];
  const int   start_a = start[arow];

  float h_own = 0.f;
  __shared__ float red[4][4][16][32];                 // [gate][kw][batch][col]
  __shared__ __align__(16) unsigned short hbf[16][32];

  const float* xrow   = x + (size_t)arow * Tn * Dn + kb + koff;
  const float* xres_p = x + (size_t)bq   * Tn * Dn + jg;

  // prologue: x(0) into registers
  f32x4 xa[4][2];
  #pragma unroll
  for (int s = 0; s < 4; ++s) {
    xa[s][0] = *(const f32x4*)(xrow + s * 32);
    xa[s][1] = *(const f32x4*)(xrow + s * 32 + 4);
  }

  #pragma unroll 1
  for (int t = 0; t < Tn; ++t) {
    // -------- phase A: convert x(t) and run input-projection MFMAs --------
    const float xres = xres_p[(size_t)t * Dn];
    bf16x8 xf[4];
    #pragma unroll
    for (int s = 0; s < 4; ++s) {
      unsigned d0, d1, d2, d3;
      asm("v_cvt_pk_bf16_f32 %0, %1, %2" : "=v"(d0) : "v"(xa[s][0][0]), "v"(xa[s][0][1]));
      asm("v_cvt_pk_bf16_f32 %0, %1, %2" : "=v"(d1) : "v"(xa[s][0][2]), "v"(xa[s][0][3]));
      asm("v_cvt_pk_bf16_f32 %0, %1, %2" : "=v"(d2) : "v"(xa[s][1][0]), "v"(xa[s][1][1]));
      asm("v_cvt_pk_bf16_f32 %0, %1, %2" : "=v"(d3) : "v"(xa[s][1][2]), "v"(xa[s][1][3]));
      union { u32x4 u; bf16x8 v; } xu;
      xu.u[0] = d0; xu.u[1] = d1; xu.u[2] = d2; xu.u[3] = d3;
      xf[s] = xu.v;
    }
    f32x4 ar = {0,0,0,0}, az = {0,0,0,0}, anx = {0,0,0,0}, anh = {0,0,0,0};
    #pragma unroll
    for (int s = 0; s < 4; ++s) {
      ar  = __builtin_amdgcn_mfma_f32_16x16x32_bf16(xf[s], wif[0][s], ar,  0, 0, 0);
      az  = __builtin_amdgcn_mfma_f32_16x16x32_bf16(xf[s], wif[1][s], az,  0, 0, 0);
      anx = __builtin_amdgcn_mfma_f32_16x16x32_bf16(xf[s], wif[2][s], anx, 0, 0, 0);
    }

    // -------- phase C: self-validating h load (parity in bf16 LSBs) --------
    if (t > 0) {
      const bool am = (start_a < t);
      const unsigned short* hp =
          ring + (size_t)(t & 1) * (Bn * Hn) + arow * Hn + kb + koff;
      const unsigned pexp = (unsigned)((t >> 1) & 1);  // expected tag this step
      u32x4 a0, a1, a2, a3;
      for (;;) {
        asm volatile("global_load_dwordx4 %0, %1, off sc0 sc1" : "=v"(a0) : "v"(hp)      : "memory");
        asm volatile("global_load_dwordx4 %0, %1, off sc0 sc1" : "=v"(a1) : "v"(hp + 32) : "memory");
        asm volatile("global_load_dwordx4 %0, %1, off sc0 sc1" : "=v"(a2) : "v"(hp + 64) : "memory");
        asm volatile("global_load_dwordx4 %0, %1, off sc0 sc1" : "=v"(a3) : "v"(hp + 96) : "memory");
        asm volatile("s_waitcnt vmcnt(0)" ::: "memory");
        __builtin_amdgcn_sched_barrier(0);
        const unsigned andv = a0[0] & a0[1] & a0[2] & a0[3] & a1[0] & a1[1] & a1[2] & a1[3]
                            & a2[0] & a2[1] & a2[2] & a2[3] & a3[0] & a3[1] & a3[2] & a3[3];
        const unsigned orv  = a0[0] | a0[1] | a0[2] | a0[3] | a1[0] | a1[1] | a1[2] | a1[3]
                            | a2[0] | a2[1] | a2[2] | a2[3] | a3[0] | a3[1] | a3[2] | a3[3];
        const int ok = pexp ? ((andv & 0x00010001u) == 0x00010001u)
                            : ((orv  & 0x00010001u) == 0u);
        if (__all(ok)) break;
      }
      union { u32x4 u; bf16x8 v; } c0, c1, c2, c3;
      const u32x4 zz = {0, 0, 0, 0};
      c0.u = am ? a0 : zz; c1.u = am ? a1 : zz; c2.u = am ? a2 : zz; c3.u = am ? a3 : zz;
      ar  = __builtin_amdgcn_mfma_f32_16x16x32_bf16(c0.v, whf[0][0], ar,  0, 0, 0);
      az  = __builtin_amdgcn_mfma_f32_16x16x32_bf16(c0.v, whf[1][0], az,  0, 0, 0);
      anh = __builtin_amdgcn_mfma_f32_16x16x32_bf16(c0.v, whf[2][0], anh, 0, 0, 0);
      ar  = __builtin_amdgcn_mfma_f32_16x16x32_bf16(c1.v, whf[0][1], ar,  0, 0, 0);
      az  = __builtin_amdgcn_mfma_f32_16x16x32_bf16(c1.v, whf[1][1], az,  0, 0, 0);
      anh = __builtin_amdgcn_mfma_f32_16x16x32_bf16(c1.v, whf[2][1], anh, 0, 0, 0);
      ar  = __builtin_amdgcn_mfma_f32_16x16x32_bf16(c2.v, whf[0][2], ar,  0, 0, 0);
      az  = __builtin_amdgcn_mfma_f32_16x16x32_bf16(c2.v, whf[1][2], az,  0, 0, 0);
      anh = __builtin_amdgcn_mfma_f32_16x16x32_bf16(c2.v, whf[2][2], anh, 0, 0, 0);
      ar  = __builtin_amdgcn_mfma_f32_16x16x32_bf16(c3.v, whf[0][3], ar,  0, 0, 0);
      az  = __builtin_amdgcn_mfma_f32_16x16x32_bf16(c3.v, whf[1][3], az,  0, 0, 0);
      anh = __builtin_amdgcn_mfma_f32_16x16x32_bf16(c3.v, whf[2][3], anh, 0, 0, 0);
    }

    // -------- phase D: cross-wave reduce + gates + state update --------
    #pragma unroll
    for (int i = 0; i < 4; ++i) {
      const int r_ = (lane >> 4) * 4 + i;
      const int c_ = jw * 16 + (lane & 15);
      red[0][kw][r_][c_] = ar[i];
      red[1][kw][r_][c_] = az[i];
      red[2][kw][r_][c_] = anx[i];
      red[3][kw][r_][c_] = anh[i];
    }
    // prefetch x(t+1) — latency hides under reduce/publish/validate
    {
      const int tn_ = (t + 1 < Tn) ? (t + 1) : t;
      const float* xt = xrow + (size_t)tn_ * Dn;
      #pragma unroll
      for (int s = 0; s < 4; ++s) {
        xa[s][0] = *(const f32x4*)(xt + s * 32);
        xa[s][1] = *(const f32x4*)(xt + s * 32 + 4);
      }
    }
    __syncthreads();
    float sr = bias_r, sz = bias_z, snx = bias_nx, snh = bias_nh;
    #pragma unroll
    for (int k2 = 0; k2 < 4; ++k2) {
      sr  += red[0][k2][bq][jj];
      sz  += red[1][k2][bq][jj];
      snx += red[2][k2][bq][jj];
      snh += red[3][k2][bq][jj];
    }
    const float r  = 1.f / (1.f + __expf(-sr));
    const float z  = 1.f / (1.f + __expf(-sz));
    const float ea = __expf(2.f * (snx + r * snh));
    const float n  = 1.f - 2.f / (ea + 1.f);             // NaN-safe tanh
    const float hm = (start_g < t) ? h_own : 0.f;
    const float hn = (1.f - z) * n + z * hm;
    h_own = hn;

    const size_t oo = ((size_t)bq * Tn + t) * Hn + jg;
    out[oo] = xres + hn;
    out[(size_t)Bn * Tn * Hn + oo] = hn;

    // tag for generation t+1 into the bf16 LSB
    const unsigned short ptag = (unsigned short)(((t + 1) >> 1) & 1);
    hbf[bq][jj] = (unsigned short)((f2bf(hn) & 0xFFFEu) | ptag);
    __syncthreads();

    // -------- phase E: publish (fire-and-forget, self-validating atoms) ----
    if (wv == 0) {
      const int l = lane;
      const u32x4 hv = *(const u32x4*)(&hbf[0][0] + ((l >> 2) * 32 + (l & 3) * 8));
      unsigned short* dst = ring + (size_t)((t + 1) & 1) * (Bn * Hn)
                          + (l >> 2) * Hn + blockIdx.x * JWG + (l & 3) * 8;
      asm volatile("global_store_dwordx4 %0, %1, off sc0 sc1" :: "v"(dst), "v"(hv) : "memory");
    }
  }
}

extern "C" void kernel_launch(void* const* d_in, const int* in_sizes, int n_in,
                              void* d_out, int out_size, void* d_ws, size_t ws_size,
                              hipStream_t stream) {
  const float* x     = (const float*)d_in[0];
  const int*   start = (const int*)d_in[1];
  const float* w_ih  = (const float*)d_in[2];
  const float* w_hh  = (const float*)d_in[3];
  const float* b_ih  = (const float*)d_in[4];
  const float* b_hh  = (const float*)d_in[5];
  float* out = (float*)d_out;

  unsigned short* ring = (unsigned short*)d_ws;   // [2][16][512] bf16 ping-pong

  // Init so neither buffer's pattern matches its first expected parity:
  // buf0 first read at t=2 expects LSB=1 -> init 0x00; buf1 first read at t=1
  // expects LSB=0 -> init 0x01 (ushort 0x0101, LSB=1). Graph-captured, replay-safe.
  hipMemsetAsync(ring, 0x00, 16384, stream);
  hipMemsetAsync((char*)ring + 16384, 0x01, 16384, stream);
  hipLaunchKernelGGL(gru_scan, dim3(NWG), dim3(NTH), 0, stream,
                     x, start, w_ih, w_hh, b_ih, b_hh, out, ring);
}